// Round 1
// baseline (36691.943 us; speedup 1.0000x reference)
//
#include <hip/hip_runtime.h>
#include <hip/hip_bf16.h>
#include <stdint.h>

#define DIMS 2048
#define SEQ  4096
#define NBLK 128   // persistent blocks for the recurrence
#define RPB  16    // rows of W_hh per block (NBLK*RPB == DIMS)

// ---------- helpers ----------
__device__ __forceinline__ unsigned pk_bf16(float a, float b) {
  // round-to-nearest-even bf16, packed (a -> low16, b -> high16)
  unsigned ua = __float_as_uint(a);
  ua += 0x7fffu + ((ua >> 16) & 1u);
  unsigned ub = __float_as_uint(b);
  ub += 0x7fffu + ((ub >> 16) & 1u);
  return (ua >> 16) | (ub & 0xffff0000u);
}
__device__ __forceinline__ float bflo(unsigned u) { return __uint_as_float(u << 16); }
__device__ __forceinline__ float bfhi(unsigned u) { return __uint_as_float(u & 0xffff0000u); }

// ---------- Kernel A: Z = X @ W_hi^T + b  (fp32, written into d_out) ----------
// grid (SEQ/64, DIMS/64), 256 threads, 64x64 tile, BK=32
__global__ __launch_bounds__(256) void gemm_z(const float* __restrict__ X,
                                              const float* __restrict__ W,
                                              const float* __restrict__ bias,
                                              float* __restrict__ Z) {
  __shared__ float xs[64][33];
  __shared__ float ws[64][33];
  const int tid = threadIdx.x;
  const int tx = tid & 15;   // d-dir, 4 cols each
  const int ty = tid >> 4;   // s-dir, 4 rows each
  const int s0 = blockIdx.x * 64;
  const int d0 = blockIdx.y * 64;

  float acc[4][4] = {};

  for (int k0 = 0; k0 < DIMS; k0 += 32) {
#pragma unroll
    for (int i = 0; i < 2; ++i) {
      int idx = tid + i * 256;            // 0..511 float4 slots
      int r = idx >> 3;                   // 0..63
      int c = (idx & 7) << 2;             // 0..28
      float4 xv = *(const float4*)&X[(size_t)(s0 + r) * DIMS + k0 + c];
      xs[r][c] = xv.x; xs[r][c + 1] = xv.y; xs[r][c + 2] = xv.z; xs[r][c + 3] = xv.w;
      float4 wv = *(const float4*)&W[(size_t)(d0 + r) * DIMS + k0 + c];
      ws[r][c] = wv.x; ws[r][c + 1] = wv.y; ws[r][c + 2] = wv.z; ws[r][c + 3] = wv.w;
    }
    __syncthreads();
#pragma unroll
    for (int k = 0; k < 32; ++k) {
      float a_[4], b_[4];
#pragma unroll
      for (int i = 0; i < 4; ++i) a_[i] = xs[ty * 4 + i][k];
#pragma unroll
      for (int j = 0; j < 4; ++j) b_[j] = ws[tx * 4 + j][k];
#pragma unroll
      for (int i = 0; i < 4; ++i)
#pragma unroll
        for (int j = 0; j < 4; ++j) acc[i][j] += a_[i] * b_[j];
    }
    __syncthreads();
  }

  const float4 bv = *(const float4*)&bias[d0 + tx * 4];
#pragma unroll
  for (int i = 0; i < 4; ++i) {
    float4 o;
    o.x = acc[i][0] + bv.x; o.y = acc[i][1] + bv.y;
    o.z = acc[i][2] + bv.z; o.w = acc[i][3] + bv.w;
    *(float4*)&Z[(size_t)(s0 + ty * 4 + i) * DIMS + d0 + tx * 4] = o;
  }
}

// ---------- Kernel B: persistent sequential recurrence ----------
// 128 blocks x 256 threads. Block b owns rows [b*16, b*16+16) of W_hh (bf16, LDS-resident).
// Per step: poll flags -> stage h_{t-1} (LLC) into LDS -> 16 matvec rows -> tanh ->
// write out = x + h (d_out) and publish h slice (agent stores) -> release flag.
__global__ __launch_bounds__(256) void rnn_seq(const float* __restrict__ X,
                                               const float* __restrict__ Whh,
                                               const float* __restrict__ h0,
                                               float* __restrict__ ZO,   // d_out: Z in, out overwrites
                                               float* __restrict__ hb,   // ws: 2*DIMS floats (double buffer)
                                               int* __restrict__ flags)  // ws: NBLK flags, stride 16 ints
{
  __shared__ uint4  w16[16][RPB][16];  // [j4][row][kk]  : 4 bf16-pairs = 8 K-elems per uint4
  __shared__ float4 hs4[DIMS / 4];     // swizzled h_{t-1}

  const int tid = threadIdx.x;
  const int b   = blockIdx.x;
  const int r   = tid >> 4;            // 0..15  (local row; 16 consecutive lanes share a row)
  const int kk  = tid & 15;            // 0..15  (128-element K-chunk per thread)
  const int grow = b * RPB + r;        // global row

  // ---- one-time: pack this block's W_hh rows into LDS as bf16 pairs ----
  {
    const float* wrow = Whh + (size_t)grow * DIMS + kk * 128;
#pragma unroll 4
    for (int j4 = 0; j4 < 16; ++j4) {
      float4 f0 = *(const float4*)(wrow + j4 * 8);
      float4 f1 = *(const float4*)(wrow + j4 * 8 + 4);
      w16[j4][r][kk] = make_uint4(pk_bf16(f0.x, f0.y), pk_bf16(f0.z, f0.w),
                                  pk_bf16(f1.x, f1.y), pk_bf16(f1.z, f1.w));
    }
  }
  // ---- publish h0 slice into buffer 1 (consumed at t=0) ----
  if (tid < RPB) {
    __hip_atomic_store(&hb[DIMS + b * RPB + tid], h0[b * RPB + tid],
                       __ATOMIC_RELAXED, __HIP_MEMORY_SCOPE_AGENT);
  }
  __syncthreads();
  if (tid == 0)
    __hip_atomic_store(&flags[b * 16], 1, __ATOMIC_RELEASE, __HIP_MEMORY_SCOPE_AGENT);

  for (int t = 0; t < SEQ; ++t) {
    // ---- wait for all blocks to have published h_{t-1} ----
    const int target = t + 1;
    if (tid < NBLK) {
      while (__hip_atomic_load(&flags[tid * 16], __ATOMIC_ACQUIRE,
                               __HIP_MEMORY_SCOPE_AGENT) < target) { }
    }
    __syncthreads();

    // ---- stage h_{t-1} from LLC into LDS (bank-swizzled float4) ----
    {
      const unsigned long long* src64 =
          (const unsigned long long*)(hb + ((t + 1) & 1) * DIMS);
#pragma unroll
      for (int c = 0; c < 2; ++c) {
        int L = tid + c * 256;  // float4 index 0..511
        unsigned long long a  = __hip_atomic_load(src64 + 2 * L,     __ATOMIC_RELAXED, __HIP_MEMORY_SCOPE_AGENT);
        unsigned long long bq = __hip_atomic_load(src64 + 2 * L + 1, __ATOMIC_RELAXED, __HIP_MEMORY_SCOPE_AGENT);
        int kko = L >> 5, j2o = L & 31;
        float4 v;
        v.x = __uint_as_float((unsigned)a);
        v.y = __uint_as_float((unsigned)(a >> 32));
        v.z = __uint_as_float((unsigned)bq);
        v.w = __uint_as_float((unsigned)(bq >> 32));
        hs4[kko * 32 + (j2o ^ (kko & 7))] = v;
      }
    }
    __syncthreads();

    // ---- matvec: row `grow`, this thread covers K = [kk*128, kk*128+128) ----
    float acc = 0.f;
#pragma unroll
    for (int j4 = 0; j4 < 16; ++j4) {
      uint4 w = w16[j4][r][kk];
      float4 ha = hs4[kk * 32 + ((2 * j4)     ^ (kk & 7))];
      float4 hc = hs4[kk * 32 + ((2 * j4 + 1) ^ (kk & 7))];
      acc += bflo(w.x) * ha.x + bfhi(w.x) * ha.y + bflo(w.y) * ha.z + bfhi(w.y) * ha.w;
      acc += bflo(w.z) * hc.x + bfhi(w.z) * hc.y + bflo(w.w) * hc.z + bfhi(w.w) * hc.w;
    }
    // reduce 16 K-chunk partials (16 consecutive lanes per row)
#pragma unroll
    for (int off = 8; off > 0; off >>= 1) acc += __shfl_xor(acc, off, 16);

    if (kk == 0) {
      const size_t idx = (size_t)t * DIMS + grow;
      float y = acc + ZO[idx];          // Z_t[row]
      float hcur = tanhf(y);
      ZO[idx] = X[idx] + hcur;          // residual output overwrites Z
      __hip_atomic_store(&hb[(t & 1) * DIMS + grow], hcur,
                         __ATOMIC_RELAXED, __HIP_MEMORY_SCOPE_AGENT);
    }
    __syncthreads();   // all rows of this block published (vmcnt drained at barrier)
    if (tid == 0)
      __hip_atomic_store(&flags[b * 16], t + 2, __ATOMIC_RELEASE, __HIP_MEMORY_SCOPE_AGENT);
  }
}

// ---------- launch ----------
extern "C" void kernel_launch(void* const* d_in, const int* in_sizes, int n_in,
                              void* d_out, int out_size, void* d_ws, size_t ws_size,
                              hipStream_t stream) {
  (void)in_sizes; (void)n_in; (void)out_size; (void)ws_size;
  const float* X    = (const float*)d_in[0];
  const float* Whi  = (const float*)d_in[1];
  const float* Whh  = (const float*)d_in[2];
  const float* bias = (const float*)d_in[3];
  const float* h0   = (const float*)d_in[4];
  float* out = (float*)d_out;

  float* hb   = (float*)d_ws;                                   // 2*DIMS floats
  int*  flags = (int*)((char*)d_ws + 2 * DIMS * sizeof(float)); // NBLK*16 ints

  hipMemsetAsync(flags, 0, NBLK * 16 * sizeof(int), stream);

  dim3 g(SEQ / 64, DIMS / 64);
  gemm_z<<<g, 256, 0, stream>>>(X, Whi, bias, out);
  rnn_seq<<<NBLK, 256, 0, stream>>>(X, Whh, h0, out, hb, flags);
}

// Round 2
// 13151.065 us; speedup vs baseline: 2.7900x; 2.7900x over previous
//
#include <hip/hip_runtime.h>
#include <hip/hip_bf16.h>
#include <stdint.h>

#define DIMS 2048
#define SEQ  4096
#define NBLK 128   // persistent blocks for the recurrence
#define RPB  16    // rows of W_hh per block (NBLK*RPB == DIMS)

// ---------- helpers ----------
__device__ __forceinline__ unsigned pk_bf16(float a, float b) {
  // round-to-nearest-even bf16, packed (a -> low16, b -> high16)
  unsigned ua = __float_as_uint(a);
  ua += 0x7fffu + ((ua >> 16) & 1u);
  unsigned ub = __float_as_uint(b);
  ub += 0x7fffu + ((ub >> 16) & 1u);
  return (ua >> 16) | (ub & 0xffff0000u);
}
__device__ __forceinline__ float bflo(unsigned u) { return __uint_as_float(u << 16); }
__device__ __forceinline__ float bfhi(unsigned u) { return __uint_as_float(u & 0xffff0000u); }

// ---------- Kernel A: Z = X @ W_hi^T + b  (fp32, written into d_out) ----------
// grid (SEQ/64, DIMS/64), 256 threads, 64x64 tile, BK=32
__global__ __launch_bounds__(256) void gemm_z(const float* __restrict__ X,
                                              const float* __restrict__ W,
                                              const float* __restrict__ bias,
                                              float* __restrict__ Z) {
  __shared__ float xs[64][33];
  __shared__ float ws[64][33];
  const int tid = threadIdx.x;
  const int tx = tid & 15;   // d-dir, 4 cols each
  const int ty = tid >> 4;   // s-dir, 4 rows each
  const int s0 = blockIdx.x * 64;
  const int d0 = blockIdx.y * 64;

  float acc[4][4] = {};

  for (int k0 = 0; k0 < DIMS; k0 += 32) {
#pragma unroll
    for (int i = 0; i < 2; ++i) {
      int idx = tid + i * 256;            // 0..511 float4 slots
      int r = idx >> 3;                   // 0..63
      int c = (idx & 7) << 2;             // 0..28
      float4 xv = *(const float4*)&X[(size_t)(s0 + r) * DIMS + k0 + c];
      xs[r][c] = xv.x; xs[r][c + 1] = xv.y; xs[r][c + 2] = xv.z; xs[r][c + 3] = xv.w;
      float4 wv = *(const float4*)&W[(size_t)(d0 + r) * DIMS + k0 + c];
      ws[r][c] = wv.x; ws[r][c + 1] = wv.y; ws[r][c + 2] = wv.z; ws[r][c + 3] = wv.w;
    }
    __syncthreads();
#pragma unroll
    for (int k = 0; k < 32; ++k) {
      float a_[4], b_[4];
#pragma unroll
      for (int i = 0; i < 4; ++i) a_[i] = xs[ty * 4 + i][k];
#pragma unroll
      for (int j = 0; j < 4; ++j) b_[j] = ws[tx * 4 + j][k];
#pragma unroll
      for (int i = 0; i < 4; ++i)
#pragma unroll
        for (int j = 0; j < 4; ++j) acc[i][j] += a_[i] * b_[j];
    }
    __syncthreads();
  }

  const float4 bv = *(const float4*)&bias[d0 + tx * 4];
#pragma unroll
  for (int i = 0; i < 4; ++i) {
    float4 o;
    o.x = acc[i][0] + bv.x; o.y = acc[i][1] + bv.y;
    o.z = acc[i][2] + bv.z; o.w = acc[i][3] + bv.w;
    *(float4*)&Z[(size_t)(s0 + ty * 4 + i) * DIMS + d0 + tx * 4] = o;
  }
}

// ---------- Kernel B: persistent sequential recurrence ----------
// 128 blocks x 256 threads. Block b owns rows [b*16, b*16+16) of W_hh (bf16, LDS-resident).
// Protocol uses ONLY relaxed agent-scope atomics (per-instruction sc1 -> LLC-coherent,
// no buffer_inv / wbl2 cache maintenance). Ordering: h stores are drained by the
// vmcnt(0) inside __syncthreads before the flag store issues.
__global__ __launch_bounds__(256) void rnn_seq(const float* __restrict__ X,
                                               const float* __restrict__ Whh,
                                               const float* __restrict__ h0,
                                               float* __restrict__ ZO,   // d_out: Z in, out overwrites
                                               float* __restrict__ hb,   // ws: 2*DIMS floats (double buffer)
                                               int* __restrict__ flags)  // ws: NBLK flags, stride 16 ints
{
  __shared__ uint4  w16[16][RPB][16];  // [j4][row][kk]  : 4 bf16-pairs = 8 K-elems per uint4
  __shared__ float4 hs4[DIMS / 4];     // swizzled h_{t-1}

  const int tid = threadIdx.x;
  const int b   = blockIdx.x;
  const int r   = tid >> 4;            // 0..15  (local row; 16 consecutive lanes share a row)
  const int kk  = tid & 15;            // 0..15  (128-element K-chunk per thread)
  const int grow = b * RPB + r;        // global row

  // ---- one-time: pack this block's W_hh rows into LDS as bf16 pairs ----
  {
    const float* wrow = Whh + (size_t)grow * DIMS + kk * 128;
#pragma unroll 4
    for (int j4 = 0; j4 < 16; ++j4) {
      float4 f0 = *(const float4*)(wrow + j4 * 8);
      float4 f1 = *(const float4*)(wrow + j4 * 8 + 4);
      w16[j4][r][kk] = make_uint4(pk_bf16(f0.x, f0.y), pk_bf16(f0.z, f0.w),
                                  pk_bf16(f1.x, f1.y), pk_bf16(f1.z, f1.w));
    }
  }
  // ---- publish h0 slice into buffer 1 (consumed at t=0) ----
  if (tid < RPB) {
    __hip_atomic_store(&hb[DIMS + b * RPB + tid], h0[b * RPB + tid],
                       __ATOMIC_RELAXED, __HIP_MEMORY_SCOPE_AGENT);
  }
  // prefetch Z[0][grow], X[0][grow] for the first step (off critical path)
  float zpre = 0.f, xpre = 0.f;
  if (kk == 0) {
    zpre = ZO[grow];
    xpre = X[grow];
  }
  __syncthreads();   // drains h0 stores (vmcnt)
  if (tid == 0)
    __hip_atomic_store(&flags[b * 16], 1, __ATOMIC_RELAXED, __HIP_MEMORY_SCOPE_AGENT);

  for (int t = 0; t < SEQ; ++t) {
    // ---- wait for all blocks to have published h_{t-1} (relaxed polls, no cache ops) ----
    const int target = t + 1;
    if (tid < NBLK) {
      while (__hip_atomic_load(&flags[tid * 16], __ATOMIC_RELAXED,
                               __HIP_MEMORY_SCOPE_AGENT) < target) { }
    }
    __syncthreads();

    // ---- stage h_{t-1} from LLC into LDS (bank-swizzled float4) ----
    {
      const unsigned long long* src64 =
          (const unsigned long long*)(hb + ((t + 1) & 1) * DIMS);
#pragma unroll
      for (int c = 0; c < 2; ++c) {
        int L = tid + c * 256;  // float4 index 0..511
        unsigned long long a  = __hip_atomic_load(src64 + 2 * L,     __ATOMIC_RELAXED, __HIP_MEMORY_SCOPE_AGENT);
        unsigned long long bq = __hip_atomic_load(src64 + 2 * L + 1, __ATOMIC_RELAXED, __HIP_MEMORY_SCOPE_AGENT);
        int kko = L >> 5, j2o = L & 31;
        float4 v;
        v.x = __uint_as_float((unsigned)a);
        v.y = __uint_as_float((unsigned)(a >> 32));
        v.z = __uint_as_float((unsigned)bq);
        v.w = __uint_as_float((unsigned)(bq >> 32));
        hs4[kko * 32 + (j2o ^ (kko & 7))] = v;
      }
    }
    __syncthreads();

    // ---- matvec: row `grow`, this thread covers K = [kk*128, kk*128+128) ----
    float acc = 0.f;
#pragma unroll
    for (int j4 = 0; j4 < 16; ++j4) {
      uint4 w = w16[j4][r][kk];
      float4 ha = hs4[kk * 32 + ((2 * j4)     ^ (kk & 7))];
      float4 hc = hs4[kk * 32 + ((2 * j4 + 1) ^ (kk & 7))];
      acc += bflo(w.x) * ha.x + bfhi(w.x) * ha.y + bflo(w.y) * ha.z + bfhi(w.y) * ha.w;
      acc += bflo(w.z) * hc.x + bfhi(w.z) * hc.y + bflo(w.w) * hc.z + bfhi(w.w) * hc.w;
    }
    // reduce 16 K-chunk partials (16 consecutive lanes per row)
#pragma unroll
    for (int off = 8; off > 0; off >>= 1) acc += __shfl_xor(acc, off, 16);

    float outval = 0.f;
    if (kk == 0) {
      float y = acc + zpre;             // Z_t[row] was prefetched
      float hcur = tanhf(y);
      outval = xpre + hcur;             // residual
      __hip_atomic_store(&hb[(t & 1) * DIMS + grow], hcur,
                         __ATOMIC_RELAXED, __HIP_MEMORY_SCOPE_AGENT);
    }
    __syncthreads();   // vmcnt(0): h stores acked at LLC before flag publish
    if (tid == 0)
      __hip_atomic_store(&flags[b * 16], t + 2, __ATOMIC_RELAXED, __HIP_MEMORY_SCOPE_AGENT);

    // off-critical-path: write residual output, prefetch next step's Z/X rows
    if (kk == 0) {
      ZO[(size_t)t * DIMS + grow] = outval;
      if (t + 1 < SEQ) {
        zpre = ZO[(size_t)(t + 1) * DIMS + grow];
        xpre = X[(size_t)(t + 1) * DIMS + grow];
      }
    }
  }
}

// ---------- launch ----------
extern "C" void kernel_launch(void* const* d_in, const int* in_sizes, int n_in,
                              void* d_out, int out_size, void* d_ws, size_t ws_size,
                              hipStream_t stream) {
  (void)in_sizes; (void)n_in; (void)out_size; (void)ws_size;
  const float* X    = (const float*)d_in[0];
  const float* Whi  = (const float*)d_in[1];
  const float* Whh  = (const float*)d_in[2];
  const float* bias = (const float*)d_in[3];
  const float* h0   = (const float*)d_in[4];
  float* out = (float*)d_out;

  float* hb   = (float*)d_ws;                                   // 2*DIMS floats
  int*  flags = (int*)((char*)d_ws + 2 * DIMS * sizeof(float)); // NBLK*16 ints

  hipMemsetAsync(flags, 0, NBLK * 16 * sizeof(int), stream);

  dim3 g(SEQ / 64, DIMS / 64);
  gemm_z<<<g, 256, 0, stream>>>(X, Whi, bias, out);
  rnn_seq<<<NBLK, 256, 0, stream>>>(X, Whh, h0, out, hb, flags);
}